// Round 5
// baseline (250.980 us; speedup 1.0000x reference)
//
#include <hip/hip_runtime.h>

// B=32, C=3, H=512, W=512 -> 96 flat images. ONE kernel per (img, 16x16-pooled tile):
//  phase 0: Haar DWT -> cA 70x70 fp32 tile in LDS; interior cH/cV -> d_out high.
//  2 ic-chunks: conv1(1->16, fp32 VALU)+relu+pool -> h1 chunk f16 channel-last LDS,
//               conv2(16->8) as MFMA f16 (taps decomposed, K=32 = 4taps x 8ic).
//  epilogue: pool via in-lane max + shfl_xor(16), conv3(8->4) via LDS h2 buffer.
// d_out = low (1,572,864 f32) ++ high (12,582,912 f32)

typedef _Float16 f16x8 __attribute__((ext_vector_type(8)));
typedef float    f32x4 __attribute__((ext_vector_type(4)));

__global__ __launch_bounds__(256, 3) void fused_all_kernel(
    const float* __restrict__ x,
    const float* __restrict__ w1, const float* __restrict__ b1,
    const float* __restrict__ w2, const float* __restrict__ b2,
    const float* __restrict__ w3, const float* __restrict__ b3,
    float* __restrict__ outLow, float* __restrict__ outHigh)
{
    __shared__ __align__(16) float    ca[70 * 72];       // cA fp32, interior rows/cols 3..66
    __shared__ __align__(16) _Float16 h1s[38 * 36 * 8];  // [row][col][8ic] f16; rows 34-37 = zeros

    int img = blockIdx.x >> 4;
    int t   = blockIdx.x & 15;
    int ty = t >> 2, tx = t & 3;
    int hy0 = ty * 32 - 1, hx0 = tx * 32 - 1;   // h1 tile origin (34x34 incl halo)
    int cy0 = ty * 64 - 3, cx0 = tx * 64 - 3;   // cA tile origin (70x70)

    const float* xi = x + img * 262144;
    float* hb = outHigh + img * 131072;

    int lane = threadIdx.x & 63;
    int wid  = threadIdx.x >> 6;
    int q = lane >> 4, m = lane & 15;
    int ppy = m >> 2, ppx = m & 3;              // pixel within 4x4 M-tile
    int wy = wid >> 1, wx = wid & 1;            // wave quadrant (16x16 pre-pool)

    // ---- B fragments: w2 as f16, B[k=quad*8+j][n=lane&15]; k-group quad = tap ----
    f16x8 Bf[2][3];
    #pragma unroll
    for (int c = 0; c < 2; ++c)
        #pragma unroll
        for (int s = 0; s < 3; ++s) {
            f16x8 bf;
            #pragma unroll
            for (int j = 0; j < 8; ++j) {
                int tt = s * 4 + q;
                float wvv = 0.f;
                if (m < 8 && tt < 9) wvv = w2[(m * 16 + (c * 8 + j)) * 9 + tt];
                bf[j] = (_Float16)wvv;
            }
            Bf[c][s] = bf;
        }
    float bb2 = 0.f;
    if (m < 8) bb2 = b2[m];

    // ---- Phase 0a: interior 64x64 cA (coalesced), cH/cV -> global ----
    #pragma unroll
    for (int k = 0; k < 4; ++k) {
        int i = threadIdx.x + k * 256;
        int row = i >> 4, cg = i & 15;
        int gy = ty * 64 + row;
        int gx = tx * 64 + cg * 4;
        const float* r0 = xi + (2 * gy) * 512 + 2 * gx;
        const float* r1 = r0 + 512;
        float4 t0 = *(const float4*)(r0);
        float4 t1 = *(const float4*)(r0 + 4);
        float4 u0 = *(const float4*)(r1);
        float4 u1 = *(const float4*)(r1 + 4);
        float4 vA, vH, vV;
        vA.x = (t0.x + t0.y + u0.x + u0.y) * 0.5f;
        vH.x = (t0.x + t0.y - u0.x - u0.y) * 0.5f;
        vV.x = (t0.x - t0.y + u0.x - u0.y) * 0.5f;
        vA.y = (t0.z + t0.w + u0.z + u0.w) * 0.5f;
        vH.y = (t0.z + t0.w - u0.z - u0.w) * 0.5f;
        vV.y = (t0.z - t0.w + u0.z - u0.w) * 0.5f;
        vA.z = (t1.x + t1.y + u1.x + u1.y) * 0.5f;
        vH.z = (t1.x + t1.y - u1.x - u1.y) * 0.5f;
        vV.z = (t1.x - t1.y + u1.x - u1.y) * 0.5f;
        vA.w = (t1.z + t1.w + u1.z + u1.w) * 0.5f;
        vH.w = (t1.z + t1.w - u1.z - u1.w) * 0.5f;
        vV.w = (t1.z - t1.w + u1.z - u1.w) * 0.5f;
        int po = (gy << 8) + gx;
        *(float4*)(hb + po) = vH;
        *(float4*)(hb + 65536 + po) = vV;
        float* cp = ca + (row + 3) * 72 + cg * 4 + 3;
        cp[0] = vA.x; cp[1] = vA.y; cp[2] = vA.z; cp[3] = vA.w;
    }

    // ---- Phase 0b: 3-wide halo ring of cA (804 points), vA only ----
    for (int i = threadIdx.x; i < 804; i += 256) {
        int r, c;
        if (i < 210)      { r = i / 70;              c = i - r * 70; }
        else if (i < 420) { int j = i - 210; r = 67 + j / 70; c = j - (j / 70) * 70; }
        else              { int j = i - 420; r = 3 + j / 6; int k6 = j - (j / 6) * 6;
                            c = (k6 < 3) ? k6 : (64 + k6); }
        int gy = cy0 + r, gx = cx0 + c;
        float v = 0.f;
        if ((unsigned)gy < 256u && (unsigned)gx < 256u) {
            const float* p0 = xi + (2 * gy) * 512 + 2 * gx;
            float2 a = *(const float2*)(p0);
            float2 b = *(const float2*)(p0 + 512);
            v = (a.x + a.y + b.x + b.y) * 0.5f;
        }
        ca[r * 72 + c] = v;
    }

    // ---- Zero rows 34..37 of h1s (A-source for padded taps) ----
    {
        f16x8 z;
        #pragma unroll
        for (int j = 0; j < 8; ++j) z[j] = (_Float16)0.f;
        for (int i = threadIdx.x; i < 144; i += 256)
            *(f16x8*)(h1s + (34 * 36 + i) * 8) = z;
    }

    // ---- Per-lane A-operand tap offsets (in f16 elements) ----
    int ky0 = (q >= 3) ? 1 : 0, kx0 = (q >= 3) ? 0 : q;          // taps 0..3
    int t1q = q + 4;
    int ky1 = (t1q >= 6) ? 2 : 1, kx1 = t1q - ky1 * 3;           // taps 4..7
    int off0 = ((ppy + ky0) * 36 + (ppx + kx0)) * 8;
    int off1 = ((ppy + ky1) * 36 + (ppx + kx1)) * 8;
    int off2 = ((ppy + 2) * 36 + (ppx + 2)) * 8;                 // tap 8 (q==0)
    int zoff = ((34 + ppy) * 36 + ppx) * 8;                      // zero rows
    bool z2 = (q != 0);

    f32x4 acc[16];
    #pragma unroll
    for (int i = 0; i < 16; ++i) acc[i] = (f32x4){0.f, 0.f, 0.f, 0.f};

    __syncthreads();

    // ---- 2 chunks: conv1 (8 oc, fp32 VALU) -> h1s f16; conv2 accumulate (MFMA) ----
    #pragma unroll
    for (int cc = 0; cc < 2; ++cc) {
        if (cc) __syncthreads();   // prev chunk's conv2 reads before h1s overwrite

        #pragma unroll 1
        for (int k = 0; k < 5; ++k) {
            int i = threadIdx.x + k * 256;
            if (i < 1156) {
                int hy = i / 34, hx = i - hy * 34;
                const float* pb = ca + (2 * hy) * 72 + 2 * hx;
                float patch[4][4];
                #pragma unroll
                for (int r = 0; r < 4; ++r) {
                    float2 a = *(const float2*)(pb + r * 72);
                    float2 b = *(const float2*)(pb + r * 72 + 2);
                    patch[r][0] = a.x; patch[r][1] = a.y;
                    patch[r][2] = b.x; patch[r][3] = b.y;
                }
                bool oob = ((unsigned)(hy0 + hy) >= 128u) | ((unsigned)(hx0 + hx) >= 128u);
                f16x8 ov;
                #pragma unroll
                for (int og = 0; og < 2; ++og) {
                    #pragma unroll
                    for (int o = 0; o < 4; ++o) {
                        int oc = cc * 8 + og * 4 + o;
                        float p00 = 0.f, p01 = 0.f, p10 = 0.f, p11 = 0.f;
                        #pragma unroll
                        for (int ky = 0; ky < 3; ++ky)
                            #pragma unroll
                            for (int kx = 0; kx < 3; ++kx) {
                                float wvv = w1[oc * 9 + ky * 3 + kx];   // uniform s_load
                                p00 += patch[ky][kx]         * wvv;
                                p01 += patch[ky][kx + 1]     * wvv;
                                p10 += patch[ky + 1][kx]     * wvv;
                                p11 += patch[ky + 1][kx + 1] * wvv;
                            }
                        float mm = fmaxf(fmaxf(p00, p01), fmaxf(p10, p11)) + b1[oc];
                        mm = fmaxf(mm, 0.f);
                        ov[og * 4 + o] = (_Float16)(oob ? 0.f : mm);
                    }
                }
                *(f16x8*)(h1s + (hy * 36 + hx) * 8) = ov;
            }
        }
        __syncthreads();

        // conv2: per wave, 16 M-tiles (4x4 pixel blocks) x 3 MFMA K-steps
        #pragma unroll
        for (int mt = 0; mt < 16; ++mt) {
            int my = mt >> 2, mx = mt & 3;
            int pbase = ((wy * 16 + my * 4) * 36 + (wx * 16 + mx * 4)) * 8;
            f16x8 a0 = *(const f16x8*)(h1s + pbase + off0);
            f16x8 a1 = *(const f16x8*)(h1s + pbase + off1);
            int a2i = z2 ? zoff : (pbase + off2);
            f16x8 a2 = *(const f16x8*)(h1s + a2i);
            acc[mt] = __builtin_amdgcn_mfma_f32_16x16x32_f16(a0, Bf[cc][0], acc[mt], 0, 0, 0);
            acc[mt] = __builtin_amdgcn_mfma_f32_16x16x32_f16(a1, Bf[cc][1], acc[mt], 0, 0, 0);
            acc[mt] = __builtin_amdgcn_mfma_f32_16x16x32_f16(a2, Bf[cc][2], acc[mt], 0, 0, 0);
        }
    }

    // ---- Pool (in-lane + shfl_xor 16) + bias/relu -> h2 buffer (aliases ca) ----
    // D layout: lane holds pixel (q*4+reg) = (py=q, px=reg), oc = m. Pool rows pair q^1.
    float* h2b = (float*)ca;
    #pragma unroll
    for (int mt = 0; mt < 16; ++mt) {
        int my = mt >> 2, mx = mt & 3;
        float u0 = fmaxf(acc[mt][0], acc[mt][1]);
        float u1 = fmaxf(acc[mt][2], acc[mt][3]);
        float v0 = fmaxf(u0, __shfl_xor(u0, 16, 64));
        float v1 = fmaxf(u1, __shfl_xor(u1, 16, 64));
        float h20 = fmaxf(v0 + bb2, 0.f);
        float h21 = fmaxf(v1 + bb2, 0.f);
        if (m < 8 && (q & 1) == 0) {
            int Yp = wy * 8 + my * 2 + (q >> 1);
            int Xp = wx * 8 + mx * 2;
            h2b[(Yp * 16 + Xp) * 8 + m]     = h20;
            h2b[(Yp * 16 + Xp + 1) * 8 + m] = h21;
        }
    }
    __syncthreads();

    // ---- conv3 (1x1, 8->4) -> low ----
    {
        int Yp = threadIdx.x >> 4, Xp = threadIdx.x & 15;
        const float* hv = h2b + (Yp * 16 + Xp) * 8;
        float4 va = *(const float4*)(hv);
        float4 vb = *(const float4*)(hv + 4);
        float h2v[8] = {va.x, va.y, va.z, va.w, vb.x, vb.y, vb.z, vb.w};
        float* dst = outLow + img * 16384;
        int pos = (ty * 16 + Yp) * 64 + tx * 16 + Xp;
        #pragma unroll
        for (int oc3 = 0; oc3 < 4; ++oc3) {
            float s = b3[oc3];
            #pragma unroll
            for (int ic = 0; ic < 8; ++ic) s += w3[oc3 * 8 + ic] * h2v[ic];
            dst[oc3 * 4096 + pos] = s;
        }
    }
}

extern "C" void kernel_launch(void* const* d_in, const int* in_sizes, int n_in,
                              void* d_out, int out_size, void* d_ws, size_t ws_size,
                              hipStream_t stream) {
    const float* x  = (const float*)d_in[0];
    const float* w1 = (const float*)d_in[1];
    const float* b1 = (const float*)d_in[2];
    const float* w2 = (const float*)d_in[3];
    const float* b2 = (const float*)d_in[4];
    const float* w3 = (const float*)d_in[5];
    const float* b3 = (const float*)d_in[6];
    float* out     = (float*)d_out;
    float* outLow  = out;                 // 1,572,864 floats
    float* outHigh = out + 1572864;       // 12,582,912 floats

    fused_all_kernel<<<1536, 256, 0, stream>>>(x, w1, b1, w2, b2, w3, b3,
                                               outLow, outHigh);
}

// Round 6
// 245.778 us; speedup vs baseline: 1.0212x; 1.0212x over previous
//
#include <hip/hip_runtime.h>

// B=32, C=3, H=512, W=512 -> 96 flat images. ONE kernel per (img, 16x16-pooled tile):
//  phase 0: Haar DWT -> cA 70x70 f16 tile in LDS; interior cH/cV -> d_out high.
//  conv1(1->16, fp32 VALU)+relu+pool -> h1 [34][34][16ic] f16 LDS (single pass).
//  conv2(16->8) MFMA f16: per M-tile a single f32x4 acc, 5 MFMAs (K=32 = 2 taps x 16 ic,
//    tap 9 slot zero-weighted). Pool via in-lane fmax + shfl_xor(16) -> h2 LDS (aliases cA).
//  conv3(8->4, 1x1) -> d_out low.  No big register state lives across phases (r5 spilled).
// d_out = low (1,572,864 f32) ++ high (12,582,912 f32)

typedef _Float16 f16x8 __attribute__((ext_vector_type(8)));
typedef _Float16 f16x2 __attribute__((ext_vector_type(2)));
typedef float    f32x4 __attribute__((ext_vector_type(4)));

__global__ __launch_bounds__(256, 3) void fused_all_kernel(
    const float* __restrict__ x,
    const float* __restrict__ w1, const float* __restrict__ b1,
    const float* __restrict__ w2, const float* __restrict__ b2,
    const float* __restrict__ w3, const float* __restrict__ b3,
    float* __restrict__ outLow, float* __restrict__ outHigh)
{
    __shared__ __align__(16) float    smem0[2450];        // ca f16[70*70] (9800B), later h2b f32[2048]
    __shared__ __align__(16) _Float16 h1s[34 * 34 * 16];  // [row][col][16 ic], 36992 B

    _Float16* ca  = (_Float16*)smem0;
    float*    h2b = smem0;

    int img = blockIdx.x >> 4;
    int t   = blockIdx.x & 15;
    int ty = t >> 2, tx = t & 3;
    int hy0 = ty * 32 - 1, hx0 = tx * 32 - 1;   // h1 tile origin (34x34 incl halo)
    int cy0 = ty * 64 - 3, cx0 = tx * 64 - 3;   // cA tile origin (70x70)

    const float* xi = x + img * 262144;
    float* hb = outHigh + img * 131072;

    int lane = threadIdx.x & 63;
    int wid  = threadIdx.x >> 6;
    int q = lane >> 4, m = lane & 15;
    int ppy = m >> 2, ppx = m & 3;              // pixel within 4x4 M-tile
    int wy = wid >> 1, wx = wid & 1;            // wave quadrant (16x16 pre-pool)

    // ---- Phase 0a: interior 64x64 cA (coalesced), cH/cV -> global ----
    #pragma unroll
    for (int k = 0; k < 4; ++k) {
        int i = threadIdx.x + k * 256;
        int row = i >> 4, cg = i & 15;
        int gy = ty * 64 + row;
        int gx = tx * 64 + cg * 4;
        const float* r0 = xi + (2 * gy) * 512 + 2 * gx;
        const float* r1 = r0 + 512;
        float4 t0 = *(const float4*)(r0);
        float4 t1 = *(const float4*)(r0 + 4);
        float4 u0 = *(const float4*)(r1);
        float4 u1 = *(const float4*)(r1 + 4);
        float4 vA, vH, vV;
        vA.x = (t0.x + t0.y + u0.x + u0.y) * 0.5f;
        vH.x = (t0.x + t0.y - u0.x - u0.y) * 0.5f;
        vV.x = (t0.x - t0.y + u0.x - u0.y) * 0.5f;
        vA.y = (t0.z + t0.w + u0.z + u0.w) * 0.5f;
        vH.y = (t0.z + t0.w - u0.z - u0.w) * 0.5f;
        vV.y = (t0.z - t0.w + u0.z - u0.w) * 0.5f;
        vA.z = (t1.x + t1.y + u1.x + u1.y) * 0.5f;
        vH.z = (t1.x + t1.y - u1.x - u1.y) * 0.5f;
        vV.z = (t1.x - t1.y + u1.x - u1.y) * 0.5f;
        vA.w = (t1.z + t1.w + u1.z + u1.w) * 0.5f;
        vH.w = (t1.z + t1.w - u1.z - u1.w) * 0.5f;
        vV.w = (t1.z - t1.w + u1.z - u1.w) * 0.5f;
        int po = (gy << 8) + gx;
        *(float4*)(hb + po) = vH;
        *(float4*)(hb + 65536 + po) = vV;
        _Float16* cp = ca + (row + 3) * 70 + cg * 4 + 3;
        cp[0] = (_Float16)vA.x; cp[1] = (_Float16)vA.y;
        cp[2] = (_Float16)vA.z; cp[3] = (_Float16)vA.w;
    }

    // ---- Phase 0b: 3-wide halo ring of cA (804 points), vA only ----
    for (int i = threadIdx.x; i < 804; i += 256) {
        int r, c;
        if (i < 210)      { r = i / 70;              c = i - r * 70; }
        else if (i < 420) { int j = i - 210; r = 67 + j / 70; c = j - (j / 70) * 70; }
        else              { int j = i - 420; r = 3 + j / 6; int k6 = j - (j / 6) * 6;
                            c = (k6 < 3) ? k6 : (64 + k6); }   // {0,1,2,67,68,69}
        int gy = cy0 + r, gx = cx0 + c;
        float v = 0.f;
        if ((unsigned)gy < 256u && (unsigned)gx < 256u) {
            const float* p0 = xi + (2 * gy) * 512 + 2 * gx;
            float2 a = *(const float2*)(p0);
            float2 b = *(const float2*)(p0 + 512);
            v = (a.x + a.y + b.x + b.y) * 0.5f;
        }
        ca[r * 70 + c] = (_Float16)v;
    }

    __syncthreads();

    // ---- conv1 (1->16) + relu + pool2 -> h1s [34][34][16] f16, single pass ----
    #pragma unroll 1
    for (int k = 0; k < 5; ++k) {
        int i = threadIdx.x + k * 256;
        if (i < 1156) {
            int hy = i / 34, hx = i - hy * 34;
            const _Float16* pb = ca + (2 * hy) * 70 + 2 * hx;
            float patch[4][4];
            #pragma unroll
            for (int r = 0; r < 4; ++r) {
                f16x2 a = *(const f16x2*)(pb + r * 70);
                f16x2 b = *(const f16x2*)(pb + r * 70 + 2);
                patch[r][0] = (float)a.x; patch[r][1] = (float)a.y;
                patch[r][2] = (float)b.x; patch[r][3] = (float)b.y;
            }
            bool oob = ((unsigned)(hy0 + hy) >= 128u) | ((unsigned)(hx0 + hx) >= 128u);
            f16x8 ov0, ov1;
            #pragma unroll
            for (int oc = 0; oc < 16; ++oc) {
                float p00 = 0.f, p01 = 0.f, p10 = 0.f, p11 = 0.f;
                #pragma unroll
                for (int ky = 0; ky < 3; ++ky)
                    #pragma unroll
                    for (int kx = 0; kx < 3; ++kx) {
                        float wvv = w1[oc * 9 + ky * 3 + kx];   // uniform s_load
                        p00 += patch[ky][kx]         * wvv;
                        p01 += patch[ky][kx + 1]     * wvv;
                        p10 += patch[ky + 1][kx]     * wvv;
                        p11 += patch[ky + 1][kx + 1] * wvv;
                    }
                float mm = fmaxf(fmaxf(p00, p01), fmaxf(p10, p11)) + b1[oc];
                mm = fmaxf(mm, 0.f);
                _Float16 hv = (_Float16)(oob ? 0.f : mm);
                if (oc < 8) ov0[oc] = hv; else ov1[oc - 8] = hv;
            }
            *(f16x8*)(h1s + (hy * 34 + hx) * 16)     = ov0;
            *(f16x8*)(h1s + (hy * 34 + hx) * 16 + 8) = ov1;
        }
    }

    __syncthreads();
    // (all ca reads done; smem0 may now be reused as h2b)

    // ---- B fragments: 5 K-steps, K=32 = 2 taps x 16 ic; tap index tt = 2s + (q>>1) ----
    // B[k=q*8+j][n=lane&15]: n = oc (8 valid), ic = (q&1)*8 + j, tt>8 -> 0
    f16x8 Bf[5];
    #pragma unroll
    for (int s = 0; s < 5; ++s) {
        int tt = 2 * s + (q >> 1);
        f16x8 bf;
        #pragma unroll
        for (int j = 0; j < 8; ++j) {
            int ic = (q & 1) * 8 + j;
            float wvv = 0.f;
            if (m < 8 && tt < 9) wvv = w2[(m * 16 + ic) * 9 + tt];
            bf[j] = (_Float16)wvv;
        }
        Bf[s] = bf;
    }
    float bb2 = (m < 8) ? b2[m] : 0.f;

    // Per-lane A offsets (f16 elements): tap tt clamped to 8 when tt==9 (B=0 there)
    int offA[5];
    #pragma unroll
    for (int s = 0; s < 5; ++s) {
        int tt = 2 * s + (q >> 1);
        int ttc = (tt > 8) ? 8 : tt;
        int ky = ttc / 3, kx = ttc - 3 * ky;
        offA[s] = ((ppy + ky) * 34 + (ppx + kx)) * 16 + (q & 1) * 8;
    }

    // ---- conv2 MFMA per M-tile (single acc), pool, -> h2b ----
    #pragma unroll 4
    for (int mt = 0; mt < 16; ++mt) {
        int my = mt >> 2, mx = mt & 3;
        int pbase = ((wy * 16 + my * 4) * 34 + (wx * 16 + mx * 4)) * 16;
        f32x4 acc = (f32x4){0.f, 0.f, 0.f, 0.f};
        #pragma unroll
        for (int s = 0; s < 5; ++s) {
            f16x8 a = *(const f16x8*)(h1s + pbase + offA[s]);
            acc = __builtin_amdgcn_mfma_f32_16x16x32_f16(a, Bf[s], acc, 0, 0, 0);
        }
        // D: lane(q,m) reg r -> pixel (py=q, px=r), oc=m. Pool cols in-lane, rows via xor16.
        float u0 = fmaxf(acc[0], acc[1]);
        float u1 = fmaxf(acc[2], acc[3]);
        float v0 = fmaxf(u0, __shfl_xor(u0, 16, 64));
        float v1 = fmaxf(u1, __shfl_xor(u1, 16, 64));
        float h20 = fmaxf(v0 + bb2, 0.f);
        float h21 = fmaxf(v1 + bb2, 0.f);
        if (m < 8 && (q & 1) == 0) {
            int Yp = wy * 8 + my * 2 + (q >> 1);
            int Xp = wx * 8 + mx * 2;
            h2b[(Yp * 16 + Xp) * 8 + m]     = h20;
            h2b[(Yp * 16 + Xp + 1) * 8 + m] = h21;
        }
    }
    __syncthreads();

    // ---- conv3 (1x1, 8->4) -> low ----
    {
        int Yp = threadIdx.x >> 4, Xp = threadIdx.x & 15;
        const float* hv = h2b + (Yp * 16 + Xp) * 8;
        float4 va = *(const float4*)(hv);
        float4 vb = *(const float4*)(hv + 4);
        float h2v[8] = {va.x, va.y, va.z, va.w, vb.x, vb.y, vb.z, vb.w};
        float* dst = outLow + img * 16384;
        int pos = (ty * 16 + Yp) * 64 + tx * 16 + Xp;
        #pragma unroll
        for (int oc3 = 0; oc3 < 4; ++oc3) {
            float s = b3[oc3];
            #pragma unroll
            for (int ic = 0; ic < 8; ++ic) s += w3[oc3 * 8 + ic] * h2v[ic];
            dst[oc3 * 4096 + pos] = s;
        }
    }
}

extern "C" void kernel_launch(void* const* d_in, const int* in_sizes, int n_in,
                              void* d_out, int out_size, void* d_ws, size_t ws_size,
                              hipStream_t stream) {
    const float* x  = (const float*)d_in[0];
    const float* w1 = (const float*)d_in[1];
    const float* b1 = (const float*)d_in[2];
    const float* w2 = (const float*)d_in[3];
    const float* b2 = (const float*)d_in[4];
    const float* w3 = (const float*)d_in[5];
    const float* b3 = (const float*)d_in[6];
    float* out     = (float*)d_out;
    float* outLow  = out;                 // 1,572,864 floats
    float* outHigh = out + 1572864;       // 12,582,912 floats

    fused_all_kernel<<<1536, 256, 0, stream>>>(x, w1, b1, w2, b2, w3, b3,
                                               outLow, outHigh);
}